// Round 6
// baseline (293.529 us; speedup 1.0000x reference)
//
#include <hip/hip_runtime.h>
#include <stdint.h>

#define NBLK 512
#define NTHR 512

// ---------------------------------------------------------------------------
// Wave reduce: bitwise-identical to all previously passing kernels.
// ---------------------------------------------------------------------------
__device__ __forceinline__ float wave_reduce(float s) {
    #pragma unroll
    for (int off = 32; off > 0; off >>= 1) s += __shfl_down(s, off);
    return s;
}

// Ascending-chunk float4 dot (verbatim round-2 body; passed absmax 0.0).
__device__ __forceinline__ float dot_row_aligned(const float* __restrict__ w,
                                                 const float* __restrict__ xv,
                                                 int cols, int lane) {
    const float4* wp = (const float4*)w;
    const float4* xp = (const float4*)xv;
    int nv = cols >> 2;
    float s = 0.0f;
    int g = lane;
    for (; g + 192 < nv; g += 256) {
        float4 x0 = xp[g];       float4 a0 = wp[g];
        float4 x1 = xp[g + 64];  float4 a1 = wp[g + 64];
        float4 x2 = xp[g + 128]; float4 a2 = wp[g + 128];
        float4 x3 = xp[g + 192]; float4 a3 = wp[g + 192];
        s += a0.x*x0.x + a0.y*x0.y + a0.z*x0.z + a0.w*x0.w;
        s += a1.x*x1.x + a1.y*x1.y + a1.z*x1.z + a1.w*x1.w;
        s += a2.x*x2.x + a2.y*x2.y + a2.z*x2.z + a2.w*x2.w;
        s += a3.x*x3.x + a3.y*x3.y + a3.z*x3.z + a3.w*x3.w;
    }
    for (; g < nv; g += 64) {
        float4 xq = xp[g]; float4 a = wp[g];
        s += a.x*xq.x + a.y*xq.y + a.z*xq.z + a.w*xq.w;
    }
    return s;
}

// ---------------------------------------------------------------------------
// Cross-block communication protocol (NO per-barrier cache maintenance):
//  * producers write cross-phase scalars with relaxed AGENT-scope atomic
//    stores -> sc0/sc1 write-through, visible at LLC when vmcnt retires;
//  * __syncthreads() drains each wave's vmcnt (compiler emits full waitcnt
//    before s_barrier), so by the time thread 0 bumps the barrier counter,
//    every store of this block is LLC-visible;
//  * readers touch these addresses for the FIRST time after the barrier, so
//    their L1/L2 hold no stale copies -> plain cached loads are legal;
//  * barrier itself: monotone per-slot counter, atomic-add + relaxed poll.
// ---------------------------------------------------------------------------
__device__ __forceinline__ void st_agent(float* p, float v) {
    __hip_atomic_store(p, v, __ATOMIC_RELAXED, __HIP_MEMORY_SCOPE_AGENT);
}

__device__ __forceinline__ void gbar(int* __restrict__ bar, int k) {
    __syncthreads();   // includes s_waitcnt vmcnt(0) -> our stores are at LLC
    if (threadIdx.x == 0) {
        __hip_atomic_fetch_add(&bar[k], 1, __ATOMIC_RELAXED, __HIP_MEMORY_SCOPE_AGENT);
        while (__hip_atomic_load(&bar[k], __ATOMIC_RELAXED, __HIP_MEMORY_SCOPE_AGENT) < NBLK) {
            __builtin_amdgcn_s_sleep(4);
        }
    }
    __syncthreads();
}

// ---------------------------------------------------------------------------
// Fused whole-network kernel, NORMAL launch (graph-capturable), 512 blocks x
// 512 threads = 2 blocks/CU guaranteed-resident (26 KB LDS, <=128 VGPR,
// 16/32 waves per CU). Phase bodies + row->wave mappings are verbatim from
// the round-2 kernel that passed with absmax 0.0; only the cross-block store
// instruction and barrier implementation differ.
// ---------------------------------------------------------------------------
__global__ __launch_bounds__(NTHR, 4) void fused_k(
    const float* __restrict__ state, const float* __restrict__ x,
    const float* __restrict__ ts,
    const float* __restrict__ inW0, const float* __restrict__ inb0,
    const float* __restrict__ inW1, const float* __restrict__ inb1,
    const float* __restrict__ inW2, const float* __restrict__ inb2,
    const float* __restrict__ oW0, const float* __restrict__ ob0,
    const float* __restrict__ oW1, const float* __restrict__ ob1,
    const float* __restrict__ oW2, const float* __restrict__ ob2,
    float* __restrict__ h0, float* __restrict__ h1, float* __restrict__ pr,
    float* __restrict__ g0, float* __restrict__ g1, float* __restrict__ out,
    int* __restrict__ bar)
{
    const float CONV = 1000.0f;
    __shared__ float s_cw[32 * 33];
    __shared__ float s_spb[32 * 33];
    __shared__ float s_cpb[32 * 33];
    __shared__ float s_s[32], s_c[32];
    __shared__ float s_cpg[64];

    int tid  = threadIdx.x;
    int lane = tid & 63;
    int gw   = blockIdx.x * 8 + (tid >> 6);   // 0..4095

    // ---------------- L1: h0 = relu(inW0 @ [x; ts]), row gw (stride 2049) ---
    {
        const float* w = inW0 + (size_t)gw * 2049;
        const int n = 2048;
        float sum = 0.0f;
        int mis = (int)(((uintptr_t)w >> 2) & 3);
        int start = (4 - mis) & 3;
        if (lane < start) sum += w[lane] * x[lane];
        int nv = (n - start) >> 2;
        const float4* wp = (const float4*)(w + start);
        const float* xs = x + start;
        int g = lane;
        for (; g + 192 < nv; g += 256) {
            float4 u0 = wp[g];
            float4 u1 = wp[g + 64];
            float4 u2 = wp[g + 128];
            float4 u3 = wp[g + 192];
            const float* x0 = xs + 4 * g;
            sum += u0.x * x0[0]   + u0.y * x0[1]   + u0.z * x0[2]   + u0.w * x0[3];
            sum += u1.x * x0[256] + u1.y * x0[257] + u1.z * x0[258] + u1.w * x0[259];
            sum += u2.x * x0[512] + u2.y * x0[513] + u2.z * x0[514] + u2.w * x0[515];
            sum += u3.x * x0[768] + u3.y * x0[769] + u3.z * x0[770] + u3.w * x0[771];
        }
        for (; g < nv; g += 64) {
            float4 u = wp[g];
            const float* xp2 = xs + 4 * g;
            sum += u.x * xp2[0] + u.y * xp2[1] + u.z * xp2[2] + u.w * xp2[3];
        }
        int t = start + nv * 4 + lane;
        if (t < n) sum += w[t] * x[t];
        if (lane == 0) sum += w[n] * ts[0];
        sum = wave_reduce(sum);
        if (lane == 0) st_agent(&h0[gw], fmaxf(sum + inb0[gw], 0.0f));
    }
    gbar(bar, 0);

    // ---------------- L2: h1 = relu(inW1 @ h0), row gw -----------------------
    {
        float s = dot_row_aligned(inW1 + (size_t)gw * 4096, h0, 4096, lane);
        s = wave_reduce(s);
        if (lane == 0) st_agent(&h1[gw], fmaxf(s + inb1[gw], 0.0f));
    }
    gbar(bar, 1);

    // ---------------- L3: pr = inW2 @ h1 (no relu), 2112 rows ---------------
    {
        int r3 = -1;
        if ((gw & 1) == 0) r3 = gw >> 1;
        else { int q = gw >> 1; if (q >= 1984) r3 = 2048 + (q - 1984); }
        if (r3 >= 0) {
            float s = dot_row_aligned(inW2 + (size_t)r3 * 4096, h1, 4096, lane);
            s = wave_reduce(s);
            if (lane == 0) st_agent(&pr[r3], s + inb2[r3]);
        }
    }
    gbar(bar, 2);

    // ---------------- L4: ODE (redundant per block, verbatim numerics) ------
    for (int k = tid; k < 1024; k += NTHR) {
        int p = k + (k >> 5);
        s_cw[p] = pr[64 + k];
        float sp, cp;
        sincosf(pr[1088 + k], &sp, &cp);
        s_spb[p] = sp;
        s_cpb[p] = cp;
    }
    __syncthreads();

    {
        bool act = (tid < 32);
        int i = tid;
        float ia = 0.f, ifr = 0.f, y0a = 0.f, y0b = 0.f, y0c = 0.f;
        if (act) {
            ia  = pr[i];
            ifr = pr[32 + i];
            y0a = state[i];
            y0b = state[32 + i];
            y0c = state[64 + i];
        }
        float h = ts[0];

        float k1a=0,k1b=0,k1c=0, k2a=0,k2b=0,k2c=0, k3a=0,k3b=0,k3c=0, k4a=0,k4b=0,k4c=0;

        auto do_eval = [&](float a, float ad, float ph,
                           float& fa, float& fb, float& fc) {
            __syncthreads();
            if (act) {
                float s, c;
                sincosf(ph, &s, &c);
                s_s[i] = s; s_c[i] = c;
            }
            __syncthreads();
            if (act) {
                float si = s_s[i], ci = s_c[i];
                float ssum = 0.0f;
                #pragma unroll
                for (int j = 0; j < 32; j++) {
                    float sj = s_s[j], cj = s_c[j];
                    float sdp = sj * ci - cj * si;              // sin(ph_j - ph_i)
                    float cdp = cj * ci + sj * si;              // cos(ph_j - ph_i)
                    int p = i * 33 + j;
                    float sv = sdp * s_cpb[p] - cdp * s_spb[p]; // sin(dphi - pb)
                    ssum += s_cw[p] * sv;
                }
                fa = ad;
                fb = ifr + a * ssum;
                fc = CONV * (CONV * 0.25f * (ia - a) - ad);
            }
        };

        do_eval(y0a, y0b, y0c, k1a, k1b, k1c);
        do_eval(y0a + h * k1a / 3.0f,
                y0b + h * k1b / 3.0f,
                y0c + h * k1c / 3.0f, k2a, k2b, k2c);
        do_eval(y0a + h * (k2a - k1a / 3.0f),
                y0b + h * (k2b - k1b / 3.0f),
                y0c + h * (k2c - k1c / 3.0f), k3a, k3b, k3c);
        do_eval(y0a + h * (k1a - k2a + k3a),
                y0b + h * (k1b - k2b + k3b),
                y0c + h * (k1c - k2c + k3c), k4a, k4b, k4c);

        if (act) {
            float na = y0a + h * 0.125f * (k1a + 3.0f * (k2a + k3a) + k4a);
            float nb = y0b + h * 0.125f * (k1b + 3.0f * (k2b + k3b) + k4b);
            float nc = y0c + h * 0.125f * (k1c + 3.0f * (k2c + k3c) + k4c);
            if (blockIdx.x == 0) {
                out[i]      = na;
                out[32 + i] = nb;
                out[64 + i] = nc;
            }
            s_cpg[i]      = na * cosf(nb);  // reference quirk: "ph" = new_state[32:64]
            s_cpg[32 + i] = na * sinf(nb);
        }
    }
    __syncthreads();

    // ---------------- L5: g0 = relu(oW0 @ cpg + ob0), even waves ------------
    if ((gw & 1) == 0) {
        int r = gw >> 1;                 // 0..2047
        float sum = oW0[(size_t)r * 64 + lane] * s_cpg[lane];
        sum = wave_reduce(sum);
        if (lane == 0) st_agent(&g0[r], fmaxf(sum + ob0[r], 0.0f));
    }
    gbar(bar, 3);

    // ---------------- L6: g1 = relu(oW1 @ g0), even waves -------------------
    if ((gw & 1) == 0) {
        int r = gw >> 1;                 // 0..2047
        float s = dot_row_aligned(oW1 + (size_t)r * 2048, g0, 2048, lane);
        s = wave_reduce(s);
        if (lane == 0) st_agent(&g1[r], fmaxf(s + ob1[r], 0.0f));
    }
    gbar(bar, 4);

    // ---------------- L7: out[96:] = oW2 @ g1, every 4th wave ---------------
    if ((gw & 3) == 0) {
        int r = gw >> 2;                 // 0..1023
        float s = dot_row_aligned(oW2 + (size_t)r * 2048, g1, 2048, lane);
        s = wave_reduce(s);
        if (lane == 0) out[96 + r] = s + ob2[r];
    }
}

extern "C" void kernel_launch(void* const* d_in, const int* in_sizes, int n_in,
                              void* d_out, int out_size, void* d_ws, size_t ws_size,
                              hipStream_t stream) {
    const float* state = (const float*)d_in[0];   // 96
    const float* x     = (const float*)d_in[1];   // 2048
    const float* ts    = (const float*)d_in[2];   // 1
    const float* inW0  = (const float*)d_in[3];   // 4096 x 2049
    const float* inb0  = (const float*)d_in[4];   // 4096
    const float* inW1  = (const float*)d_in[5];   // 4096 x 4096
    const float* inb1  = (const float*)d_in[6];   // 4096
    const float* inW2  = (const float*)d_in[7];   // 2112 x 4096
    const float* inb2  = (const float*)d_in[8];   // 2112
    const float* oW0   = (const float*)d_in[9];   // 2048 x 64
    const float* ob0   = (const float*)d_in[10];  // 2048
    const float* oW1   = (const float*)d_in[11];  // 2048 x 2048
    const float* ob1   = (const float*)d_in[12];  // 2048
    const float* oW2   = (const float*)d_in[13];  // 1024 x 2048
    const float* ob2   = (const float*)d_in[14];  // 1024

    float* ws  = (float*)d_ws;
    float* h0  = ws;            // 4096
    float* h1  = ws + 4096;     // 4096
    float* pr  = ws + 8192;     // 2112
    float* g0  = ws + 10368;    // 2048
    float* g1  = ws + 12416;    // 2048
    int*   bar = (int*)(ws + 24576); // 16 ints, zeroed below each launch

    float* out = (float*)d_out; // 96 (new_state) + 1024, fp32

    // Workspace is poisoned between iterations -> re-zero the barrier counters.
    hipMemsetAsync(bar, 0, 64, stream);

    fused_k<<<NBLK, NTHR, 0, stream>>>(
        state, x, ts,
        inW0, inb0, inW1, inb1, inW2, inb2,
        oW0, ob0, oW1, ob1, oW2, ob2,
        h0, h1, pr, g0, g1, out, bar);
}

// Round 7
// 213.445 us; speedup vs baseline: 1.3752x; 1.3752x over previous
//
#include <hip/hip_runtime.h>
#include <stdint.h>

// ---------------------------------------------------------------------------
// Wave-per-row GEMV (odd-stride path, used for inW0 stride 2049).
// 256-thread block = 4 waves = 4 rows. Scalar head to 16B, scalar x loads.
// TSCOL=1: last column multiplied by ts[0] (fuses the [x, t] concat).
// amdgpu_waves_per_eu(4,4): pins MAX waves/EU at 4 (= the 16 waves/CU we
// actually launch), so the scheduler stops targeting 8+ waves/EU and uses
// the full 128-VGPR budget -> the 8-deep load cluster stays in flight
// instead of being register-sunk to ~depth-2 (VGPR_Count was 40).
// ---------------------------------------------------------------------------
template<int RELU, int TSCOL>
__global__ __launch_bounds__(256)
__attribute__((amdgpu_waves_per_eu(4, 4)))
void gemv_k(
    const float* __restrict__ W, const float* __restrict__ B,
    const float* __restrict__ x, const float* __restrict__ ts,
    float* __restrict__ y, int rows, int cols)
{
    int wv   = threadIdx.x >> 6;
    int lane = threadIdx.x & 63;
    int row  = blockIdx.x * 4 + wv;
    if (row >= rows) return;

    int n = TSCOL ? cols - 1 : cols;
    const float* w = W + (size_t)row * (size_t)cols;
    float sum = 0.0f;

    int mis = (int)(((uintptr_t)w >> 2) & 3);
    int start = (4 - mis) & 3;
    if (start > n) start = n;
    if (lane < start) sum += w[lane] * x[lane];
    int nv = (n - start) >> 2;
    const float4* wp = (const float4*)(w + start);
    const float* xs = x + start;
    int g = lane;
    for (; g + 448 < nv; g += 512) {
        float4 u0 = wp[g];
        float4 u1 = wp[g + 64];
        float4 u2 = wp[g + 128];
        float4 u3 = wp[g + 192];
        float4 u4 = wp[g + 256];
        float4 u5 = wp[g + 320];
        float4 u6 = wp[g + 384];
        float4 u7 = wp[g + 448];
        const float* x0 = xs + 4 * g;
        sum += u0.x * x0[0]    + u0.y * x0[1]    + u0.z * x0[2]    + u0.w * x0[3];
        sum += u1.x * x0[256]  + u1.y * x0[257]  + u1.z * x0[258]  + u1.w * x0[259];
        sum += u2.x * x0[512]  + u2.y * x0[513]  + u2.z * x0[514]  + u2.w * x0[515];
        sum += u3.x * x0[768]  + u3.y * x0[769]  + u3.z * x0[770]  + u3.w * x0[771];
        sum += u4.x * x0[1024] + u4.y * x0[1025] + u4.z * x0[1026] + u4.w * x0[1027];
        sum += u5.x * x0[1280] + u5.y * x0[1281] + u5.z * x0[1282] + u5.w * x0[1283];
        sum += u6.x * x0[1536] + u6.y * x0[1537] + u6.z * x0[1538] + u6.w * x0[1539];
        sum += u7.x * x0[1792] + u7.y * x0[1793] + u7.z * x0[1794] + u7.w * x0[1795];
    }
    for (; g < nv; g += 64) {
        float4 u = wp[g];
        const float* xp = xs + 4 * g;
        sum += u.x * xp[0] + u.y * xp[1] + u.z * xp[2] + u.w * xp[3];
    }
    int t = start + nv * 4 + lane;
    if (t < n) sum += w[t] * x[t];
    if (TSCOL && lane == 0) sum += w[n] * ts[0];

    #pragma unroll
    for (int off = 32; off > 0; off >>= 1) sum += __shfl_down(sum, off);

    if (lane == 0) {
        float r = sum + B[row];
        if (RELU) r = fmaxf(r, 0.0f);
        y[row] = r;
    }
}

// ---------------------------------------------------------------------------
// 1-row-per-wave GEMV for 16B-aligned-stride layers (cols % 4 == 0).
// amdgpu_waves_per_eu(4,4): see gemv_k comment — unlocks the register
// budget (128 VGPR at 4 waves/EU) so the 8-deep W+x cluster (16 live
// float4 = 64 VGPR + addressing) survives register allocation. Per-row
// accumulation order unchanged: single accumulator, ascending stride-64
// chunks, same intra-chunk FMA order, same shuffle reduce ->
// bitwise-identical outputs.
// ---------------------------------------------------------------------------
template<int RELU>
__global__ __launch_bounds__(256)
__attribute__((amdgpu_waves_per_eu(4, 4)))
void gemv1_k(
    const float* __restrict__ W, const float* __restrict__ B,
    const float* __restrict__ x, float* __restrict__ y, int cols)
{
    int row  = blockIdx.x * 4 + (threadIdx.x >> 6);
    int lane = threadIdx.x & 63;

    const float4* wp = (const float4*)(W + (size_t)row * (size_t)cols);
    const float4* xp = (const float4*)x;
    int nv = cols >> 2;

    float s = 0.0f;
    int g = lane;
    for (; g + 448 < nv; g += 512) {
        float4 xv0 = xp[g];       float4 a0 = wp[g];
        float4 xv1 = xp[g + 64];  float4 a1 = wp[g + 64];
        float4 xv2 = xp[g + 128]; float4 a2 = wp[g + 128];
        float4 xv3 = xp[g + 192]; float4 a3 = wp[g + 192];
        float4 xv4 = xp[g + 256]; float4 a4 = wp[g + 256];
        float4 xv5 = xp[g + 320]; float4 a5 = wp[g + 320];
        float4 xv6 = xp[g + 384]; float4 a6 = wp[g + 384];
        float4 xv7 = xp[g + 448]; float4 a7 = wp[g + 448];
        s += a0.x*xv0.x + a0.y*xv0.y + a0.z*xv0.z + a0.w*xv0.w;
        s += a1.x*xv1.x + a1.y*xv1.y + a1.z*xv1.z + a1.w*xv1.w;
        s += a2.x*xv2.x + a2.y*xv2.y + a2.z*xv2.z + a2.w*xv2.w;
        s += a3.x*xv3.x + a3.y*xv3.y + a3.z*xv3.z + a3.w*xv3.w;
        s += a4.x*xv4.x + a4.y*xv4.y + a4.z*xv4.z + a4.w*xv4.w;
        s += a5.x*xv5.x + a5.y*xv5.y + a5.z*xv5.z + a5.w*xv5.w;
        s += a6.x*xv6.x + a6.y*xv6.y + a6.z*xv6.z + a6.w*xv6.w;
        s += a7.x*xv7.x + a7.y*xv7.y + a7.z*xv7.z + a7.w*xv7.w;
    }
    for (; g < nv; g += 64) {
        float4 xv = xp[g];
        float4 a = wp[g];
        s += a.x*xv.x + a.y*xv.y + a.z*xv.z + a.w*xv.w;
    }

    #pragma unroll
    for (int off = 32; off > 0; off >>= 1) s += __shfl_down(s, off);

    if (lane == 0) {
        float v = s + B[row];
        if (RELU) v = fmaxf(v, 0.0f);
        y[row] = v;
    }
}

// ---------------------------------------------------------------------------
// Fused ODE + oW0 (identical numerics to the passing version).
// Every block redundantly computes the RK4-3/8 step (deterministic fp32 ->
// identical in all blocks); block 0 writes out_state; each block then does
// 4 rows of g0 = relu(ob0 + oW0 . cpg) from LDS-held cpg.
// Reference quirks preserved:
//   dy = concat([a_dot, phase_dots, a_dd]) -> phase_dots integrates slot [n:2n]
//   cpg_out uses a = new_state[:n], "ph" = new_state[n:2n]
// ---------------------------------------------------------------------------
__global__ __launch_bounds__(256) void ode_ow0_k(
    const float* __restrict__ state, const float* __restrict__ ts,
    const float* __restrict__ params,
    const float* __restrict__ oW0, const float* __restrict__ ob0,
    float* __restrict__ g0, float* __restrict__ out_state)
{
    const float CONV = 1000.0f;
    __shared__ float s_cw[32 * 33];
    __shared__ float s_spb[32 * 33];
    __shared__ float s_cpb[32 * 33];
    __shared__ float s_s[32], s_c[32];
    __shared__ float s_cpg[64];
    int tid = threadIdx.x;

    for (int k = tid; k < 1024; k += 256) {
        int p = k + (k >> 5);
        s_cw[p] = params[64 + k];
        float sp, cp;
        sincosf(params[1088 + k], &sp, &cp);
        s_spb[p] = sp;
        s_cpb[p] = cp;
    }
    __syncthreads();

    bool act = (tid < 32);
    int i = tid;
    float ia = 0.f, ifr = 0.f, y0a = 0.f, y0b = 0.f, y0c = 0.f;
    if (act) {
        ia  = params[i];
        ifr = params[32 + i];
        y0a = state[i];
        y0b = state[32 + i];
        y0c = state[64 + i];
    }
    float h = ts[0];

    float k1a=0,k1b=0,k1c=0, k2a=0,k2b=0,k2c=0, k3a=0,k3b=0,k3c=0, k4a=0,k4b=0,k4c=0;

    auto do_eval = [&](float a, float ad, float ph,
                       float& fa, float& fb, float& fc) {
        __syncthreads();
        if (act) {
            float s, c;
            sincosf(ph, &s, &c);
            s_s[i] = s; s_c[i] = c;
        }
        __syncthreads();
        if (act) {
            float si = s_s[i], ci = s_c[i];
            float ssum = 0.0f;
            #pragma unroll
            for (int j = 0; j < 32; j++) {
                float sj = s_s[j], cj = s_c[j];
                float sdp = sj * ci - cj * si;              // sin(ph_j - ph_i)
                float cdp = cj * ci + sj * si;              // cos(ph_j - ph_i)
                int p = i * 33 + j;
                float sv = sdp * s_cpb[p] - cdp * s_spb[p]; // sin(dphi - pb)
                ssum += s_cw[p] * sv;
            }
            fa = ad;
            fb = ifr + a * ssum;
            fc = CONV * (CONV * 0.25f * (ia - a) - ad);
        }
    };

    do_eval(y0a, y0b, y0c, k1a, k1b, k1c);
    do_eval(y0a + h * k1a / 3.0f,
            y0b + h * k1b / 3.0f,
            y0c + h * k1c / 3.0f, k2a, k2b, k2c);
    do_eval(y0a + h * (k2a - k1a / 3.0f),
            y0b + h * (k2b - k1b / 3.0f),
            y0c + h * (k2c - k1c / 3.0f), k3a, k3b, k3c);
    do_eval(y0a + h * (k1a - k2a + k3a),
            y0b + h * (k1b - k2b + k3b),
            y0c + h * (k1c - k2c + k3c), k4a, k4b, k4c);

    if (act) {
        float na = y0a + h * 0.125f * (k1a + 3.0f * (k2a + k3a) + k4a);
        float nb = y0b + h * 0.125f * (k1b + 3.0f * (k2b + k3b) + k4b);
        float nc = y0c + h * 0.125f * (k1c + 3.0f * (k2c + k3c) + k4c);
        if (blockIdx.x == 0) {
            out_state[i]      = na;
            out_state[32 + i] = nb;
            out_state[64 + i] = nc;
        }
        s_cpg[i]      = na * cosf(nb);  // reference quirk: "ph" = new_state[32:64]
        s_cpg[32 + i] = na * sinf(nb);
    }
    __syncthreads();

    int wv   = tid >> 6;
    int lane = tid & 63;
    int row  = blockIdx.x * 4 + wv;     // 512 blocks * 4 = 2048 rows
    float sum = oW0[(size_t)row * 64 + lane] * s_cpg[lane];
    #pragma unroll
    for (int off = 32; off > 0; off >>= 1) sum += __shfl_down(sum, off);
    if (lane == 0) g0[row] = fmaxf(sum + ob0[row], 0.0f);
}

extern "C" void kernel_launch(void* const* d_in, const int* in_sizes, int n_in,
                              void* d_out, int out_size, void* d_ws, size_t ws_size,
                              hipStream_t stream) {
    const float* state = (const float*)d_in[0];   // 96
    const float* x     = (const float*)d_in[1];   // 2048
    const float* ts    = (const float*)d_in[2];   // 1
    const float* inW0  = (const float*)d_in[3];   // 4096 x 2049
    const float* inb0  = (const float*)d_in[4];   // 4096
    const float* inW1  = (const float*)d_in[5];   // 4096 x 4096
    const float* inb1  = (const float*)d_in[6];   // 4096
    const float* inW2  = (const float*)d_in[7];   // 2112 x 4096
    const float* inb2  = (const float*)d_in[8];   // 2112
    const float* oW0   = (const float*)d_in[9];   // 2048 x 64
    const float* ob0   = (const float*)d_in[10];  // 2048
    const float* oW1   = (const float*)d_in[11];  // 2048 x 2048
    const float* ob1   = (const float*)d_in[12];  // 2048
    const float* oW2   = (const float*)d_in[13];  // 1024 x 2048
    const float* ob2   = (const float*)d_in[14];  // 1024

    float* ws  = (float*)d_ws;
    float* h0  = ws;            // 4096
    float* h1  = ws + 4096;     // 4096
    float* pr  = ws + 8192;     // 2112
    float* g0  = ws + 10368;    // 2048
    float* g1  = ws + 12416;    // 2048

    float* out = (float*)d_out; // 96 (new_state) + 1024, fp32

    gemv_k<1,1><<<1024, 256, 0, stream>>>(inW0, inb0, x, ts, h0, 4096, 2049);
    gemv1_k<1><<<1024, 256, 0, stream>>>(inW1, inb1, h0, h1, 4096);    // 4096 rows
    gemv1_k<0><<<528,  256, 0, stream>>>(inW2, inb2, h1, pr, 4096);    // 2112 rows
    ode_ow0_k<<<512, 256, 0, stream>>>(state, ts, pr, oW0, ob0, g0, out);
    gemv1_k<1><<<512,  256, 0, stream>>>(oW1, ob1, g0, g1, 2048);      // 2048 rows
    gemv1_k<0><<<256,  256, 0, stream>>>(oW2, ob2, g1, out + 96, 2048); // 1024 rows
}